// Round 10
// baseline (1331.879 us; speedup 1.0000x reference)
//
#include <hip/hip_runtime.h>
#include <hip/hip_bf16.h>

#define EPS 1e-5f

__device__ __forceinline__ int reflect_idx(int i, int n) {
    if (i < 0) return -i;
    if (i >= n) return 2 * n - 2 - i;
    return i;
}

__device__ __forceinline__ float bilin(const float* __restrict__ pb, int Hp, float sy, float sx) {
    int y0 = (int)floorf(sy), x0 = (int)floorf(sx);
    float fy = sy - y0, fx = sx - x0;
    int y0c = min(max(y0, 0), Hp - 1), y1c = min(max(y0 + 1, 0), Hp - 1);
    int x0c = min(max(x0, 0), Hp - 1), x1c = min(max(x0 + 1, 0), Hp - 1);
    float v00 = pb[y0c * Hp + x0c], v01 = pb[y0c * Hp + x1c];
    float v10 = pb[y1c * Hp + x0c], v11 = pb[y1c * Hp + x1c];
    return v00 * (1 - fy) * (1 - fx) + v01 * (1 - fy) * fx
         + v10 * fy * (1 - fx) + v11 * fy * fx;
}

// Last-block reduction: the final block of the producer grid folds the 64-slot
// striped partials into per-channel (scale, shift) in global ss. Runs ONCE.
template <int C>
__device__ __forceinline__ void tail_reduce(const float* __restrict__ part,
                                            const float* __restrict__ g,
                                            const float* __restrict__ bb,
                                            float* __restrict__ ss,
                                            unsigned* cnt, unsigned target,
                                            float invN, int tid) {
    __shared__ bool isLast;
    __threadfence();
    if (tid == 0) isLast = (atomicAdd(cnt, 1u) == target - 1u);
    __syncthreads();
    if (!isLast) return;
    for (int c = tid; c < C; c += 256) {
        float s1 = 0.f, s2 = 0.f;
#pragma unroll 8
        for (int s = 0; s < 64; ++s) {
            s1 += __hip_atomic_load(&part[s * 2 * C + 2 * c],     __ATOMIC_RELAXED, __HIP_MEMORY_SCOPE_AGENT);
            s2 += __hip_atomic_load(&part[s * 2 * C + 2 * c + 1], __ATOMIC_RELAXED, __HIP_MEMORY_SCOPE_AGENT);
        }
        float m = s1 * invN;
        float var = s2 * invN - m * m;
        float sc = g[c] * rsqrtf(var + EPS);
        ss[2 * c] = sc;
        ss[2 * c + 1] = bb[c] - m * sc;
    }
}

// ---------------- Fused build + depthwise 3x3 body (levels 0/1) ----------------
template <int LEVEL>
__device__ __forceinline__
void fused_dw_body(int bid, int tid,
                   const float* __restrict__ feat, const float* __restrict__ prev,
                   const float* __restrict__ prev_ss,
                   const float* __restrict__ wsig,
                   float* __restrict__ out, float* __restrict__ part,
                   const float* __restrict__ g, const float* __restrict__ bb,
                   float* __restrict__ ss_out, unsigned* cnt, unsigned target, float invN) {
    constexpr int C    = LEVEL == 0 ? 66 : 98;
    constexpr int H    = LEVEL == 0 ? 32 : 64;
    constexpr int TILE = 16;
    constexpr int NT   = H / TILE;
    constexpr int PXPT = (TILE * TILE) / 256;
    constexpr int WC   = LEVEL == 0 ? 4818 : 4018;
    constexpr int NF   = LEVEL == 0 ? 64 : 32;
    constexpr int Hp   = 32;
    constexpr int Cp   = 64;
    constexpr int P    = H / 8;
    constexpr float SC = 0.5f;
    constexpr int HS   = TILE + 2;
    constexpr int PSS  = (LEVEL == 0) ? 2 : 2 * Cp;

    __shared__ float sh[HS * HS];
    __shared__ float pssl[PSS];
    int tile = bid % (NT * NT);
    int c = (bid / (NT * NT)) % C;
    int b = bid / (NT * NT * C);
    int ty0 = (tile / NT) * TILE, tx0 = (tile % NT) * TILE;

    if constexpr (LEVEL != 0) {
        for (int i = tid; i < 2 * Cp; i += 256) pssl[i] = prev_ss[i];
        __syncthreads();
    }

    for (int i = tid; i < HS * HS; i += 256) {
        int h = reflect_idx(ty0 - 1 + i / HS, H);
        int w = reflect_idx(tx0 - 1 + i % HS, H);
        float val;
        if (c == 0)      val = -1.f + 2.f * w / (H - 1);
        else if (c == 1) val = -1.f + 2.f * h / (H - 1);
        else if (c < 2 + NF) val = feat[((size_t)(b * NF + c - 2) * H + h) * H + w];
        else {
            int o = c - 2 - NF;
            const float* pb = prev + (size_t)(b * Cp + o) * Hp * Hp;
            float raw = bilin(pb, Hp, (h + 0.5f) * SC - 0.5f, (w + 0.5f) * SC - 0.5f);
            val = raw * pssl[2 * o] + pssl[2 * o + 1];
        }
        sh[i] = val;
    }
    __syncthreads();

    float s1 = 0.f, s2 = 0.f;
    float* ob = out + (((size_t)(b * C + c)) * H + ty0) * H + tx0;
    float wreg[9];
    if constexpr (TILE == P) {
        const float* wb = wsig + ((size_t)(b * WC + c * 9)) * 64 + (ty0 / P) * 8 + (tx0 / P);
#pragma unroll
        for (int t = 0; t < 9; ++t) wreg[t] = wb[(size_t)t * 64];
    }
#pragma unroll
    for (int k = 0; k < PXPT; ++k) {
        int px = tid + k * 256;
        int tyy = px / TILE, txx = px % TILE;
        if constexpr (TILE != P) {
            int u = (ty0 + tyy) / P, vv = (tx0 + txx) / P;
            const float* wb = wsig + ((size_t)(b * WC + c * 9)) * 64 + u * 8 + vv;
#pragma unroll
            for (int t = 0; t < 9; ++t) wreg[t] = wb[(size_t)t * 64];
        }
        float acc = 0.f;
#pragma unroll
        for (int t = 0; t < 9; ++t)
            acc += wreg[t] * sh[(tyy + t / 3) * HS + txx + t % 3];
        ob[tyy * H + txx] = acc;
        s1 += acc; s2 += acc * acc;
    }
#pragma unroll
    for (int off = 32; off; off >>= 1) {
        s1 += __shfl_xor(s1, off);
        s2 += __shfl_xor(s2, off);
    }
    __shared__ float r1[4], r2[4];
    int wave = tid >> 6;
    if ((tid & 63) == 0) { r1[wave] = s1; r2[wave] = s2; }
    __syncthreads();
    if (tid == 0) {
        int slot = bid & 63;
        atomicAdd(&part[slot * 2 * C + 2 * c],     r1[0] + r1[1] + r1[2] + r1[3]);
        atomicAdd(&part[slot * 2 * C + 2 * c + 1], r2[0] + r2[1] + r2[2] + r2[3]);
    }
    tail_reduce<C>(part, g, bb, ss_out, cnt, target, invN, tid);
}

// ---------------- Level 0 dw + w2-transpose combined ----------------
__global__ __launch_bounds__(256)
void dw0_prep_kernel(const float* __restrict__ f1, const float* __restrict__ w0,
                     float* __restrict__ out, float* __restrict__ part,
                     const float* __restrict__ g, const float* __restrict__ bb,
                     float* __restrict__ ss_out, unsigned* cnt,
                     const float* __restrict__ w2, float* __restrict__ wT) {
    int bid = blockIdx.x;
    if (bid < 256) {
        int uv = bid & 63, b = bid >> 6;
        const float* src = w2 + (size_t)b * 1110 * 64 + uv;
        float* dst = wT + ((size_t)(b * 64 + uv)) * 1110;
        for (int i = threadIdx.x; i < 1110; i += 256) dst[i] = src[(size_t)i * 64];
        return;
    }
    fused_dw_body<0>(bid - 256, threadIdx.x, f1, nullptr, nullptr, w0, out, part,
                     g, bb, ss_out, cnt, 1056, 1.f / 4096.f);
}

__global__ __launch_bounds__(256)
void fused_dw1_kernel(const float* __restrict__ feat, const float* __restrict__ prev,
                      const float* __restrict__ prev_ss, const float* __restrict__ wsig,
                      float* __restrict__ out, float* __restrict__ part,
                      const float* __restrict__ g, const float* __restrict__ bb,
                      float* __restrict__ ss_out, unsigned* cnt) {
    fused_dw_body<1>(blockIdx.x, threadIdx.x, feat, prev, prev_ss, wsig, out, part,
                     g, bb, ss_out, cnt, 6272, 1.f / 16384.f);
}

// ---------------- Level-2 dw: register-window, no LDS in main path, bf16 out ----------
__global__ __launch_bounds__(256)
void dw2_reg_kernel(const float* __restrict__ ximg, const float* __restrict__ prev,
                    const float* __restrict__ prev_ss,
                    const float* __restrict__ wT,
                    __hip_bfloat16* __restrict__ outb, float* __restrict__ part,
                    const float* __restrict__ g, const float* __restrict__ bb,
                    float* __restrict__ ss_out, unsigned* cnt) {
    const int C = 37, H = 256, W = 256, Hp = 64, Cp = 32;
    int tid = threadIdx.x, bid = blockIdx.x;
    int rb = bid & 31;
    int c  = (bid >> 5) % C;
    int b  = bid / (32 * C);
    int ty0 = rb * 8;
    int u = rb >> 2;
    int t = tid;
    int lane = tid & 63;

    // BN (scale, shift) for upsampled-prev channel: 2 direct loads of folded ss
    float psc = 0.f, psh = 0.f;
    if (c >= 5) {
        psc = prev_ss[2 * (c - 5)];
        psh = prev_ss[2 * (c - 5) + 1];
    }

    int v = t >> 5;
    float wr[9];
    const float* wt = wT + ((size_t)(b * 64 + u * 8 + v)) * 1110 + c * 9;
#pragma unroll
    for (int tap = 0; tap < 9; ++tap) wr[tap] = wt[tap];

    int colL = (t == 0) ? 1 : t - 1;
    int colM = t;
    int colR = (t == 255) ? 254 : t + 1;

    const float* pb   = (c >= 5) ? prev + (size_t)(b * Cp + (c - 5)) * Hp * Hp : nullptr;
    const float* xim  = (c >= 2 && c < 5) ? ximg + (size_t)(b * 3 + c - 2) * H * W : nullptr;

    float fxs[3]; int x0s[3], x1s[3]; float cxs[3];
    int cols[3] = {colL, colM, colR};
#pragma unroll
    for (int j = 0; j < 3; ++j) {
        float sx = (cols[j] + 0.5f) * 0.25f - 0.5f;
        int x0 = (int)floorf(sx);
        fxs[j] = sx - x0;
        x0s[j] = min(max(x0, 0), Hp - 1);
        x1s[j] = min(max(x0 + 1, 0), Hp - 1);
        cxs[j] = -1.f + cols[j] * (2.f / 255.f);
    }

    float px[8];
#pragma unroll
    for (int k = 0; k < 8; ++k) px[k] = 0.f;

#pragma unroll
    for (int r = 0; r < 10; ++r) {
        int h = reflect_idx(ty0 - 1 + r, H);
        float bv[3];
        if (c == 0) {
            bv[0] = cxs[0]; bv[1] = cxs[1]; bv[2] = cxs[2];
        } else if (c == 1) {
            float cy = -1.f + h * (2.f / 255.f);
            bv[0] = cy; bv[1] = cy; bv[2] = cy;
        } else if (c < 5) {
            const float* row = xim + h * W;
            bv[0] = row[colL]; bv[1] = row[colM]; bv[2] = row[colR];
        } else {
            float sy = (h + 0.5f) * 0.25f - 0.5f;
            int y0 = (int)floorf(sy);
            float fy = sy - y0;
            int y0c = min(max(y0, 0), Hp - 1), y1c = min(max(y0 + 1, 0), Hp - 1);
            const float* q0 = pb + y0c * Hp;
            const float* q1 = pb + y1c * Hp;
#pragma unroll
            for (int j = 0; j < 3; ++j) {
                float a0 = q0[x0s[j]] + (q0[x1s[j]] - q0[x0s[j]]) * fxs[j];
                float a1 = q1[x0s[j]] + (q1[x1s[j]] - q1[x0s[j]]) * fxs[j];
                bv[j] = (a0 + (a1 - a0) * fy) * psc + psh;
            }
        }
#pragma unroll
        for (int dr = 0; dr < 3; ++dr) {
            int k = r - dr;
            if (k >= 0 && k < 8)
                px[k] += wr[dr * 3] * bv[0] + wr[dr * 3 + 1] * bv[1] + wr[dr * 3 + 2] * bv[2];
        }
    }

    __hip_bfloat16* ob = outb + (((size_t)(b * C + c)) * H + ty0) * W + t;
    float s1 = 0.f, s2 = 0.f;
#pragma unroll
    for (int k = 0; k < 8; ++k) {
        ob[k * W] = __float2bfloat16(px[k]);
        s1 += px[k]; s2 += px[k] * px[k];
    }
#pragma unroll
    for (int off = 32; off; off >>= 1) {
        s1 += __shfl_xor(s1, off);
        s2 += __shfl_xor(s2, off);
    }
    if (lane == 0) {
        int slot = bid & 63;
        atomicAdd(&part[slot * 2 * C + 2 * c],     s1);
        atomicAdd(&part[slot * 2 * C + 2 * c + 1], s2);
    }
    tail_reduce<37>(part, g, bb, ss_out, cnt, 4736, 1.f / 262144.f, tid);
}

// ---------------- Pointwise 1x1, small levels ----------------
template <int C, int ONC, int H, int PX_T, int OC_T>
__global__ __launch_bounds__(256)
void pw_small_kernel(const float* __restrict__ x, const float* __restrict__ wsig,
                     const float* __restrict__ ss_in,
                     float* __restrict__ out, float* __restrict__ part,
                     const float* __restrict__ g, const float* __restrict__ bb,
                     float* __restrict__ ss_out, unsigned* cnt, float invN_out,
                     int WC, int ndw) {
    constexpr int P = H / 8;
    constexpr int OC_I = ONC / OC_T;
    __shared__ float lw[ONC * C];
    __shared__ float lx[C * PX_T];
    __shared__ float ssl[2 * C];
    int tid = threadIdx.x, bid = blockIdx.x;
    int uv = bid & 63, b = bid >> 6;
    int u = uv >> 3, v = uv & 7;

    const size_t wbase = ((size_t)b * WC + ndw) * 64 + uv;
    for (int i = tid; i < ONC * C; i += 256) lw[i] = wsig[wbase + (size_t)i * 64];
    for (int i = tid; i < 2 * C; i += 256) ssl[i] = ss_in[i];
    __syncthreads();

    for (int i = tid; i < C * PX_T; i += 256) {
        int c = i / PX_T, pxl = i % PX_T;
        int h = u * P + pxl / P, w = v * P + pxl % P;
        float xv = x[(((size_t)b * C + c) * H + h) * H + w];
        lx[i] = fminf(fmaxf(xv * ssl[2 * c] + ssl[2 * c + 1], 0.f), 6.f);
    }
    __syncthreads();

    int px_id = tid % PX_T, oc_id = tid / PX_T;
    int h = u * P + px_id / P, w = v * P + px_id % P;
    float acc[OC_I];
#pragma unroll
    for (int oi = 0; oi < OC_I; ++oi) acc[oi] = 0.f;
    for (int c = 0; c < C; ++c) {
        float xv = lx[c * PX_T + px_id];
#pragma unroll
        for (int oi = 0; oi < OC_I; ++oi)
            acc[oi] += lw[(oc_id * OC_I + oi) * C + c] * xv;
    }
    float* ob = out + (((size_t)b * ONC) * H + h) * H + w;
#pragma unroll
    for (int oi = 0; oi < OC_I; ++oi)
        ob[(size_t)(oc_id * OC_I + oi) * H * H] = acc[oi];

    constexpr int GROUP = (PX_T < 64) ? PX_T : 64;
    int lane = tid & 63;
    int slot = bid & 63;
#pragma unroll
    for (int oi = 0; oi < OC_I; ++oi) {
        float s1 = acc[oi], s2 = acc[oi] * acc[oi];
#pragma unroll
        for (int off = GROUP / 2; off; off >>= 1) {
            s1 += __shfl_xor(s1, off);
            s2 += __shfl_xor(s2, off);
        }
        if ((lane & (GROUP - 1)) == 0) {
            int o = oc_id * OC_I + oi;
            atomicAdd(&part[slot * 2 * ONC + 2 * o], s1);
            atomicAdd(&part[slot * 2 * ONC + 2 * o + 1], s2);
        }
    }
    tail_reduce<ONC>(part, g, bb, ss_out, cnt, 256, invN_out, tid);
}

// ---------------- Pointwise 1x1 level 2: bf16 input, 1024 blocks ----------------
__global__ __launch_bounds__(256)
void pw2_kernel(const __hip_bfloat16* __restrict__ x, const float* __restrict__ wT,
                const float* __restrict__ ss_in,
                float* __restrict__ out, float* __restrict__ part,
                const float* __restrict__ g, const float* __restrict__ bb,
                float* __restrict__ ss_out, unsigned* cnt) {
    const int C = 37, ONC = 21, H = 256;
    __shared__ float lw[777];
    __shared__ float ssl[74];
    __shared__ float r1[4][ONC], r2[4][ONC];
    int tid = threadIdx.x, bid = blockIdx.x;
    int chunk = bid & 3;
    int uv = (bid >> 2) & 63;
    int b = bid >> 8;
    int y0 = (uv >> 3) * 32 + chunk * 8, x0 = (uv & 7) * 32;

    const float* wt = wT + ((size_t)(b * 64 + uv)) * 1110 + 333;
    for (int i = tid; i < 777; i += 256) lw[i] = wt[i];
    for (int i = tid; i < 74; i += 256) ssl[i] = ss_in[i];
    __syncthreads();

    int row = tid >> 5, col = tid & 31;
    const __hip_bfloat16* xb = x + (((size_t)(b * C)) * H + y0 + row) * H + x0 + col;
    float acc[ONC];
#pragma unroll
    for (int o = 0; o < ONC; ++o) acc[o] = 0.f;

    for (int c = 0; c < C; ++c) {
        float xv = __bfloat162float(xb[(size_t)c * H * H]);
        xv = fminf(fmaxf(xv * ssl[2 * c] + ssl[2 * c + 1], 0.f), 6.f);
#pragma unroll
        for (int o = 0; o < ONC; ++o)
            acc[o] += lw[o * C + c] * xv;
    }
    float* ob = out + (((size_t)(b * ONC)) * H + y0 + row) * H + x0 + col;
#pragma unroll
    for (int o = 0; o < ONC; ++o) ob[(size_t)o * H * H] = acc[o];

    int wave = tid >> 6, lane = tid & 63;
#pragma unroll
    for (int o = 0; o < ONC; ++o) {
        float s1 = acc[o], s2 = acc[o] * acc[o];
#pragma unroll
        for (int off = 32; off; off >>= 1) {
            s1 += __shfl_xor(s1, off);
            s2 += __shfl_xor(s2, off);
        }
        if (lane == 0) { r1[wave][o] = s1; r2[wave][o] = s2; }
    }
    __syncthreads();
    int slot = bid & 63;
    for (int o = tid; o < ONC; o += 256) {
        atomicAdd(&part[slot * 42 + 2 * o],     r1[0][o] + r1[1][o] + r1[2][o] + r1[3][o]);
        atomicAdd(&part[slot * 42 + 2 * o + 1], r2[0][o] + r2[1][o] + r2[2][o] + r2[3][o]);
    }
    tail_reduce<21>(part, g, bb, ss_out, cnt, 1024, 1.f / 262144.f, tid);
}

// ---------------- Final in-place BN (float4, grid-stride) ----------------
__global__ __launch_bounds__(256)
void finalbn_kernel(float* __restrict__ out, const float* __restrict__ ss_in) {
    __shared__ float ssl[42];
    for (int i = threadIdx.x; i < 42; i += 256) ssl[i] = ss_in[i];
    __syncthreads();
    const int total4 = 4 * 21 * 256 * 256 / 4;
    for (int idx = blockIdx.x * 256 + threadIdx.x; idx < total4; idx += gridDim.x * 256) {
        int c = (idx / (256 * 256 / 4)) % 21;
        float4 v = ((float4*)out)[idx];
        float sc = ssl[2 * c], sb = ssl[2 * c + 1];
        v.x = v.x * sc + sb; v.y = v.y * sc + sb; v.z = v.z * sc + sb; v.w = v.w * sc + sb;
        ((float4*)out)[idx] = v;
    }
}

extern "C" void kernel_launch(void* const* d_in, const int* in_sizes, int n_in,
                              void* d_out, int out_size, void* d_ws, size_t ws_size,
                              hipStream_t stream) {
    const float* x_img = (const float*)d_in[0];
    const float* f0    = (const float*)d_in[1];
    const float* f1    = (const float*)d_in[2];
    const float* w0    = (const float*)d_in[3];
    const float* w1    = (const float*)d_in[4];
    const float* w2    = (const float*)d_in[5];
    const float* g_dw0 = (const float*)d_in[6],  *b_dw0 = (const float*)d_in[7];
    const float* g_pw0 = (const float*)d_in[8],  *b_pw0 = (const float*)d_in[9];
    const float* g_dw1 = (const float*)d_in[10], *b_dw1 = (const float*)d_in[11];
    const float* g_pw1 = (const float*)d_in[12], *b_pw1 = (const float*)d_in[13];
    const float* g_dw2 = (const float*)d_in[14], *b_dw2 = (const float*)d_in[15];
    const float* g_pw2 = (const float*)d_in[16], *b_pw2 = (const float*)d_in[17];
    float* out = (float*)d_out;
    float* ws = (float*)d_ws;

    // workspace layout (floats)
    float* part_dw0 = ws;              // 64*132 = 8448
    float* part_pw0 = ws + 8448;       // 64*128 = 8192  -> 16640
    float* part_dw1 = ws + 16640;      // 64*196 = 12544 -> 29184
    float* part_pw1 = ws + 29184;      // 64*64  = 4096  -> 33280
    float* part_dw2 = ws + 33280;      // 64*74  = 4736  -> 38016
    float* part_pw2 = ws + 38016;      // 64*42  = 2688  -> 40704
    unsigned* cnts  = (unsigned*)(ws + 40704);  // 8 counters -> 40712
    float* dw0ss = ws + 40712;         // 132
    float* pw0ss = ws + 40844;         // 128
    float* dw1ss = ws + 40972;         // 196
    float* pw1ss = ws + 41168;         // 64
    float* dw2ss = ws + 41232;         // 74
    float* pw2ss = ws + 41306;         // 42 -> 41348
    float* wT     = ws + 41360;        // 4*64*1110 = 284160 -> 325520
    float* pw0raw = ws + 325520;       // 4*64*32*32 = 262144
    float* pw1raw = pw0raw + 262144;   // 4*32*64*64 = 524288
    float* bigA   = pw1raw + 524288;   // levels 0/1 dw raw (fp32)
    __hip_bfloat16* bigAb = (__hip_bfloat16*)bigA;  // level 2 dw raw (bf16)

    hipMemsetAsync(ws, 0, 40712 * sizeof(float), stream);

    // ---- Level 0 (+ w2 transpose): C=66, 32x32, out 64 ----
    dw0_prep_kernel<<<256 + 4 * 66 * 4, 256, 0, stream>>>(
        f1, w0, bigA, part_dw0, g_dw0, b_dw0, dw0ss, cnts + 0, w2, wT);
    pw_small_kernel<66, 64, 32, 16, 16><<<256, 256, 0, stream>>>(
        bigA, w0, dw0ss, pw0raw, part_pw0, g_pw0, b_pw0, pw0ss, cnts + 1,
        1.f / 4096.f, 4818, 594);
    // ---- Level 1: C=98, 64x64, out 32 ----
    fused_dw1_kernel<<<4 * 98 * 16, 256, 0, stream>>>(
        f0, pw0raw, pw0ss, w1, bigA, part_dw1, g_dw1, b_dw1, dw1ss, cnts + 2);
    pw_small_kernel<98, 32, 64, 64, 4><<<256, 256, 0, stream>>>(
        bigA, w1, dw1ss, pw1raw, part_pw1, g_pw1, b_pw1, pw1ss, cnts + 3,
        1.f / 16384.f, 4018, 882);
    // ---- Level 2: C=37, 256x256, out 21 ----
    dw2_reg_kernel<<<4 * 37 * 32, 256, 0, stream>>>(
        x_img, pw1raw, pw1ss, wT, bigAb, part_dw2, g_dw2, b_dw2, dw2ss, cnts + 4);
    pw2_kernel<<<1024, 256, 0, stream>>>(
        bigAb, wT, dw2ss, out, part_pw2, g_pw2, b_pw2, pw2ss, cnts + 5);
    finalbn_kernel<<<1024, 256, 0, stream>>>(out, pw2ss);
}

// Round 11
// 145.607 us; speedup vs baseline: 9.1471x; 9.1471x over previous
//
#include <hip/hip_runtime.h>

#define EPS 1e-5f

__device__ __forceinline__ int reflect_idx(int i, int n) {
    if (i < 0) return -i;
    if (i >= n) return 2 * n - 2 - i;
    return i;
}

__device__ __forceinline__ float bilin(const float* __restrict__ pb, int Hp, float sy, float sx) {
    int y0 = (int)floorf(sy), x0 = (int)floorf(sx);
    float fy = sy - y0, fx = sx - x0;
    int y0c = min(max(y0, 0), Hp - 1), y1c = min(max(y0 + 1, 0), Hp - 1);
    int x0c = min(max(x0, 0), Hp - 1), x1c = min(max(x0 + 1, 0), Hp - 1);
    float v00 = pb[y0c * Hp + x0c], v01 = pb[y0c * Hp + x1c];
    float v10 = pb[y1c * Hp + x0c], v11 = pb[y1c * Hp + x1c];
    return v00 * (1 - fy) * (1 - fx) + v01 * (1 - fy) * fx
         + v10 * fy * (1 - fx) + v11 * fy * fx;
}

// ---------------- Fused build + depthwise 3x3 + striped stats (levels 0/1) ----------------
template <int LEVEL, bool WRITE>
__global__ __launch_bounds__(256)
void fused_dw_kernel(const float* __restrict__ feat, const float* __restrict__ prev,
                     const float* __restrict__ pss, const float* __restrict__ wsig,
                     float* __restrict__ out, float* __restrict__ part) {
    constexpr int C    = LEVEL == 0 ? 66 : 98;
    constexpr int H    = LEVEL == 0 ? 32 : 64;
    constexpr int TILE = 16;
    constexpr int NT   = H / TILE;
    constexpr int PXPT = (TILE * TILE) / 256;
    constexpr int WC   = LEVEL == 0 ? 4818 : 4018;
    constexpr int NF   = LEVEL == 0 ? 64 : 32;
    constexpr int Hp   = 32;
    constexpr int Cp   = 64;
    constexpr int P    = H / 8;
    constexpr float SC = 0.5f;
    constexpr int HS   = TILE + 2;

    __shared__ float sh[HS * HS];
    int tid = threadIdx.x, bid = blockIdx.x;
    int tile = bid % (NT * NT);
    int c = (bid / (NT * NT)) % C;
    int b = bid / (NT * NT * C);
    int ty0 = (tile / NT) * TILE, tx0 = (tile % NT) * TILE;

    for (int i = tid; i < HS * HS; i += 256) {
        int h = reflect_idx(ty0 - 1 + i / HS, H);
        int w = reflect_idx(tx0 - 1 + i % HS, H);
        float val;
        if (c == 0)      val = -1.f + 2.f * w / (H - 1);
        else if (c == 1) val = -1.f + 2.f * h / (H - 1);
        else if (c < 2 + NF) val = feat[((size_t)(b * NF + c - 2) * H + h) * H + w];
        else {
            int o = c - 2 - NF;
            const float* pb = prev + (size_t)(b * Cp + o) * Hp * Hp;
            float raw = bilin(pb, Hp, (h + 0.5f) * SC - 0.5f, (w + 0.5f) * SC - 0.5f);
            val = raw * pss[2 * o] + pss[2 * o + 1];
        }
        sh[i] = val;
    }
    __syncthreads();

    float s1 = 0.f, s2 = 0.f;
    float* ob = out + (((size_t)(b * C + c)) * H + ty0) * H + tx0;
    float wreg[9];
    if constexpr (TILE == P) {
        const float* wb = wsig + ((size_t)(b * WC + c * 9)) * 64 + (ty0 / P) * 8 + (tx0 / P);
#pragma unroll
        for (int t = 0; t < 9; ++t) wreg[t] = wb[(size_t)t * 64];
    }
#pragma unroll
    for (int k = 0; k < PXPT; ++k) {
        int px = tid + k * 256;
        int tyy = px / TILE, txx = px % TILE;
        if constexpr (TILE != P) {
            int u = (ty0 + tyy) / P, vv = (tx0 + txx) / P;
            const float* wb = wsig + ((size_t)(b * WC + c * 9)) * 64 + u * 8 + vv;
#pragma unroll
            for (int t = 0; t < 9; ++t) wreg[t] = wb[(size_t)t * 64];
        }
        float acc = 0.f;
#pragma unroll
        for (int t = 0; t < 9; ++t)
            acc += wreg[t] * sh[(tyy + t / 3) * HS + txx + t % 3];
        if constexpr (WRITE) ob[tyy * H + txx] = acc;
        s1 += acc; s2 += acc * acc;
    }
#pragma unroll
    for (int off = 32; off; off >>= 1) {
        s1 += __shfl_xor(s1, off);
        s2 += __shfl_xor(s2, off);
    }
    __shared__ float r1[4], r2[4];
    int wave = tid >> 6;
    if ((tid & 63) == 0) { r1[wave] = s1; r2[wave] = s2; }
    __syncthreads();
    if (tid == 0) {
        int slot = bid & 63;
        atomicAdd(&part[slot * 2 * C + 2 * c],     r1[0] + r1[1] + r1[2] + r1[3]);
        atomicAdd(&part[slot * 2 * C + 2 * c + 1], r2[0] + r2[1] + r2[2] + r2[3]);
    }
}

// ---------------- Reduce 64-slot partials -> per-channel (scale, shift) ----------------
__global__ void red_kernel(const float* __restrict__ part, const float* __restrict__ g,
                           const float* __restrict__ bb, float* __restrict__ ss,
                           int C, float invN) {
    int c = threadIdx.x;
    if (c >= C) return;
    float s1 = 0.f, s2 = 0.f;
#pragma unroll 8
    for (int s = 0; s < 64; ++s) {
        s1 += part[s * 2 * C + 2 * c];
        s2 += part[s * 2 * C + 2 * c + 1];
    }
    float m = s1 * invN;
    float var = s2 * invN - m * m;
    float sc = g[c] * rsqrtf(var + EPS);
    ss[2 * c] = sc;
    ss[2 * c + 1] = bb[c] - m * sc;
}

// ---------------- Level-2 dw: column-per-thread, hoisted bilinear, direct ss ----------
__global__ __launch_bounds__(256)
void dw2_col_kernel(const float* __restrict__ ximg, const float* __restrict__ prev,
                    const float* __restrict__ pw1ss, const float* __restrict__ wsig,
                    float* __restrict__ out, float* __restrict__ part) {
    const int C = 37, H = 256, W = 256, WC = 1110, Hp = 64, Cp = 32;
    const int S = 260;
    __shared__ float sh[10 * S];
    __shared__ float pssl[64];
    __shared__ float lwv[72];
    __shared__ float r1[4], r2[4];

    int tid = threadIdx.x, bid = blockIdx.x;
    int rb = bid & 31;
    int c  = (bid >> 5) % C;
    int b  = bid / (32 * C);
    int ty0 = rb * 8;
    int u = rb >> 2;

    if (tid < 64) pssl[tid] = pw1ss[tid];
    if (tid < 72) {
        int v = tid / 9, t = tid - v * 9;
        lwv[tid] = wsig[((size_t)(b * WC + c * 9 + t)) * 64 + u * 8 + v];
    }
    __syncthreads();

    // stage halo: thread owns image column `tid`; tail threads do cols -1 / 256
    const float* pb   = (c >= 5) ? prev + (size_t)(b * Cp + (c - 5)) * Hp * Hp : nullptr;
    const float* xrow = (c >= 2 && c < 5) ? ximg + (size_t)(b * 3 + c - 2) * H * W : nullptr;
    float cx = -1.f + tid * (2.f / 255.f);
    float sxm = (tid + 0.5f) * 0.25f - 0.5f;
    int x0m = (int)floorf(sxm);
    float fxm = sxm - x0m;
    int x0cm = min(max(x0m, 0), Hp - 1), x1cm = min(max(x0m + 1, 0), Hp - 1);
    float psc = (c >= 5) ? pssl[2 * (c - 5)] : 0.f;
    float psh = (c >= 5) ? pssl[2 * (c - 5) + 1] : 0.f;

#pragma unroll
    for (int r = 0; r < 10; ++r) {
        int h = reflect_idx(ty0 - 1 + r, H);
        float val;
        if (c == 0)      val = cx;
        else if (c == 1) val = -1.f + h * (2.f / 255.f);
        else if (c < 5)  val = xrow[h * W + tid];
        else {
            float sy = (h + 0.5f) * 0.25f - 0.5f;
            int y0 = (int)floorf(sy);
            float fy = sy - y0;
            int y0c = min(max(y0, 0), Hp - 1), y1c = min(max(y0 + 1, 0), Hp - 1);
            const float* q0 = pb + y0c * Hp;
            const float* q1 = pb + y1c * Hp;
            float a0 = q0[x0cm] + (q0[x1cm] - q0[x0cm]) * fxm;
            float a1 = q1[x0cm] + (q1[x1cm] - q1[x0cm]) * fxm;
            val = (a0 + (a1 - a0) * fy) * psc + psh;
        }
        sh[r * S + tid + 1] = val;
    }
    if (tid < 20) {
        int r = tid >> 1, side = tid & 1;
        int wimg = side ? 254 : 1;               // reflect(-1)=1, reflect(256)=254
        int h = reflect_idx(ty0 - 1 + r, H);
        float val;
        if (c == 0)      val = -1.f + wimg * (2.f / 255.f);
        else if (c == 1) val = -1.f + h * (2.f / 255.f);
        else if (c < 5)  val = xrow[h * W + wimg];
        else {
            float sx = (wimg + 0.5f) * 0.25f - 0.5f;
            int x0 = (int)floorf(sx); float fx = sx - x0;
            int x0c = min(max(x0, 0), Hp - 1), x1c = min(max(x0 + 1, 0), Hp - 1);
            float sy = (h + 0.5f) * 0.25f - 0.5f;
            int y0 = (int)floorf(sy); float fy = sy - y0;
            int y0c = min(max(y0, 0), Hp - 1), y1c = min(max(y0 + 1, 0), Hp - 1);
            const float* q0 = pb + y0c * Hp;
            const float* q1 = pb + y1c * Hp;
            float a0 = q0[x0c] + (q0[x1c] - q0[x0c]) * fx;
            float a1 = q1[x0c] + (q1[x1c] - q1[x0c]) * fx;
            val = (a0 + (a1 - a0) * fy) * psc + psh;
        }
        sh[r * S + (side ? 257 : 0)] = val;
    }
    __syncthreads();

    int t = tid;
    int v = t >> 5;
    float wr[9];
#pragma unroll
    for (int tap = 0; tap < 9; ++tap) wr[tap] = lwv[v * 9 + tap];

    float px[8];
#pragma unroll
    for (int k = 0; k < 8; ++k) px[k] = 0.f;

#pragma unroll
    for (int r = 0; r < 10; ++r) {
        float L = sh[r * S + t];
        float M = sh[r * S + t + 1];
        float R = sh[r * S + t + 2];
#pragma unroll
        for (int dr = 0; dr < 3; ++dr) {
            int k = r - dr;
            if (k >= 0 && k < 8)
                px[k] += wr[dr * 3] * L + wr[dr * 3 + 1] * M + wr[dr * 3 + 2] * R;
        }
    }

    float* ob = out + (((size_t)(b * C + c)) * H + ty0) * W + t;
    float s1 = 0.f, s2 = 0.f;
#pragma unroll
    for (int k = 0; k < 8; ++k) {
        ob[k * W] = px[k];
        s1 += px[k]; s2 += px[k] * px[k];
    }
#pragma unroll
    for (int off = 32; off; off >>= 1) {
        s1 += __shfl_xor(s1, off);
        s2 += __shfl_xor(s2, off);
    }
    int wave = tid >> 6;
    if ((tid & 63) == 0) { r1[wave] = s1; r2[wave] = s2; }
    __syncthreads();
    if (tid == 0) {
        int slot = bid & 63;
        atomicAdd(&part[slot * 2 * C + 2 * c],     r1[0] + r1[1] + r1[2] + r1[3]);
        atomicAdd(&part[slot * 2 * C + 2 * c + 1], r2[0] + r2[1] + r2[2] + r2[3]);
    }
}

// ---------------- Pointwise 1x1, small levels (direct folded ss) ----------------
template <int C, int ONC, int H, int PX_T, int OC_T>
__global__ __launch_bounds__(256)
void pw_small_kernel(const float* __restrict__ x, const float* __restrict__ wsig,
                     const float* __restrict__ ss, float* __restrict__ out,
                     float* __restrict__ part, int WC, int ndw) {
    constexpr int P = H / 8;
    constexpr int OC_I = ONC / OC_T;
    __shared__ float lw[ONC * C];
    __shared__ float lx[C * PX_T];
    int tid = threadIdx.x, bid = blockIdx.x;
    int uv = bid & 63, b = bid >> 6;
    int u = uv >> 3, v = uv & 7;

    const size_t wbase = ((size_t)b * WC + ndw) * 64 + uv;
    for (int i = tid; i < ONC * C; i += 256) lw[i] = wsig[wbase + (size_t)i * 64];
    for (int i = tid; i < C * PX_T; i += 256) {
        int c = i / PX_T, pxl = i % PX_T;
        int h = u * P + pxl / P, w = v * P + pxl % P;
        float xv = x[(((size_t)b * C + c) * H + h) * H + w];
        lx[i] = fminf(fmaxf(xv * ss[2 * c] + ss[2 * c + 1], 0.f), 6.f);
    }
    __syncthreads();

    int px_id = tid % PX_T, oc_id = tid / PX_T;
    int h = u * P + px_id / P, w = v * P + px_id % P;
    float acc[OC_I];
#pragma unroll
    for (int oi = 0; oi < OC_I; ++oi) acc[oi] = 0.f;
    for (int c = 0; c < C; ++c) {
        float xv = lx[c * PX_T + px_id];
#pragma unroll
        for (int oi = 0; oi < OC_I; ++oi)
            acc[oi] += lw[(oc_id * OC_I + oi) * C + c] * xv;
    }
    float* ob = out + (((size_t)b * ONC) * H + h) * H + w;
#pragma unroll
    for (int oi = 0; oi < OC_I; ++oi)
        ob[(size_t)(oc_id * OC_I + oi) * H * H] = acc[oi];

    constexpr int GROUP = (PX_T < 64) ? PX_T : 64;
    int lane = tid & 63;
    int slot = bid & 63;
#pragma unroll
    for (int oi = 0; oi < OC_I; ++oi) {
        float s1 = acc[oi], s2 = acc[oi] * acc[oi];
#pragma unroll
        for (int off = GROUP / 2; off; off >>= 1) {
            s1 += __shfl_xor(s1, off);
            s2 += __shfl_xor(s2, off);
        }
        if ((lane & (GROUP - 1)) == 0) {
            int o = oc_id * OC_I + oi;
            atomicAdd(&part[slot * 2 * ONC + 2 * o], s1);
            atomicAdd(&part[slot * 2 * ONC + 2 * o + 1], s2);
        }
    }
}

// ---------------- Pointwise 1x1 level 2: 1024 blocks, direct dw2ss ----------------
__global__ __launch_bounds__(256)
void pw2_kernel(const float* __restrict__ x, const float* __restrict__ wsig,
                const float* __restrict__ dss,
                float* __restrict__ out, float* __restrict__ part) {
    const int C = 37, ONC = 21, H = 256, WC = 1110, NDW = 333;
    __shared__ float lw[777];
    __shared__ float ssl[74];
    __shared__ float r1[4][ONC], r2[4][ONC];
    int tid = threadIdx.x, bid = blockIdx.x;
    int chunk = bid & 3;
    int uv = (bid >> 2) & 63;
    int b = bid >> 8;
    int y0 = (uv >> 3) * 32 + chunk * 8, x0 = (uv & 7) * 32;

    for (int i = tid; i < 777; i += 256) lw[i] = wsig[((size_t)(b * WC + NDW) + i) * 64 + uv];
    if (tid < 74) ssl[tid] = dss[tid];
    __syncthreads();

    int row = tid >> 5, col = tid & 31;
    const float* xb = x + (((size_t)(b * C)) * H + y0 + row) * H + x0 + col;
    float acc[ONC];
#pragma unroll
    for (int o = 0; o < ONC; ++o) acc[o] = 0.f;

    for (int c = 0; c < C; ++c) {
        float xv = xb[(size_t)c * H * H];
        xv = fminf(fmaxf(xv * ssl[2 * c] + ssl[2 * c + 1], 0.f), 6.f);
#pragma unroll
        for (int o = 0; o < ONC; ++o)
            acc[o] += lw[o * C + c] * xv;
    }
    float* ob = out + (((size_t)(b * ONC)) * H + y0 + row) * H + x0 + col;
#pragma unroll
    for (int o = 0; o < ONC; ++o) ob[(size_t)o * H * H] = acc[o];

    int wave = tid >> 6, lane = tid & 63;
#pragma unroll
    for (int o = 0; o < ONC; ++o) {
        float s1 = acc[o], s2 = acc[o] * acc[o];
#pragma unroll
        for (int off = 32; off; off >>= 1) {
            s1 += __shfl_xor(s1, off);
            s2 += __shfl_xor(s2, off);
        }
        if (lane == 0) { r1[wave][o] = s1; r2[wave][o] = s2; }
    }
    __syncthreads();
    int slot = bid & 63;
    for (int o = tid; o < ONC; o += 256) {
        atomicAdd(&part[slot * 42 + 2 * o],     r1[0][o] + r1[1][o] + r1[2][o] + r1[3][o]);
        atomicAdd(&part[slot * 42 + 2 * o + 1], r2[0][o] + r2[1][o] + r2[2][o] + r2[3][o]);
    }
}

// ---------------- Final in-place BN (float4, direct pw2ss) ----------------
__global__ void finalbn_kernel(float* __restrict__ out, const float* __restrict__ ss) {
    int idx = blockIdx.x * 256 + threadIdx.x;
    const int total4 = 4 * 21 * 256 * 256 / 4;
    if (idx >= total4) return;
    int c = (idx / (256 * 256 / 4)) % 21;
    float4 v = ((float4*)out)[idx];
    float sc = ss[2 * c], sb = ss[2 * c + 1];
    v.x = v.x * sc + sb; v.y = v.y * sc + sb; v.z = v.z * sc + sb; v.w = v.w * sc + sb;
    ((float4*)out)[idx] = v;
}

extern "C" void kernel_launch(void* const* d_in, const int* in_sizes, int n_in,
                              void* d_out, int out_size, void* d_ws, size_t ws_size,
                              hipStream_t stream) {
    const float* x_img = (const float*)d_in[0];
    const float* f0    = (const float*)d_in[1];
    const float* f1    = (const float*)d_in[2];
    const float* w0    = (const float*)d_in[3];
    const float* w1    = (const float*)d_in[4];
    const float* w2    = (const float*)d_in[5];
    const float* g_dw0 = (const float*)d_in[6],  *b_dw0 = (const float*)d_in[7];
    const float* g_pw0 = (const float*)d_in[8],  *b_pw0 = (const float*)d_in[9];
    const float* g_dw1 = (const float*)d_in[10], *b_dw1 = (const float*)d_in[11];
    const float* g_pw1 = (const float*)d_in[12], *b_pw1 = (const float*)d_in[13];
    const float* g_dw2 = (const float*)d_in[14], *b_dw2 = (const float*)d_in[15];
    const float* g_pw2 = (const float*)d_in[16], *b_pw2 = (const float*)d_in[17];
    float* out = (float*)d_out;
    float* ws = (float*)d_ws;

    // workspace layout (floats)
    float* part_dw0 = ws;              // 64*132 = 8448
    float* part_pw0 = ws + 8448;       // 64*128 = 8192
    float* part_dw1 = ws + 16640;      // 64*196 = 12544
    float* part_pw1 = ws + 29184;      // 64*64  = 4096
    float* part_dw2 = ws + 33280;      // 64*74  = 4736
    float* part_pw2 = ws + 38016;      // 64*42  = 2688  -> parts end 40704
    float* dw0ss = ws + 40704;         // 132
    float* pw0ss = ws + 40836;         // 128
    float* dw1ss = ws + 40964;         // 196
    float* pw1ss = ws + 41160;         // 64
    float* dw2ss = ws + 41224;         // 74
    float* pw2ss = ws + 41298;         // 42 -> 41340
    float* pw0raw = ws + 41344;        // 4*64*32*32 = 262144
    float* pw1raw = pw0raw + 262144;   // 4*32*64*64 = 524288
    float* bigA   = pw1raw + 524288;   // dw raw, up to 4*37*256*256 = 9699328

    hipMemsetAsync(ws, 0, 40704 * sizeof(float), stream);

    // ---- Level 0: C=66, 32x32, out 64 ----
    fused_dw_kernel<0, true><<<4 * 66 * 4, 256, 0, stream>>>(
        f1, nullptr, nullptr, w0, bigA, part_dw0);
    red_kernel<<<1, 128, 0, stream>>>(part_dw0, g_dw0, b_dw0, dw0ss, 66, 1.f / 4096.f);
    pw_small_kernel<66, 64, 32, 16, 16><<<256, 256, 0, stream>>>(
        bigA, w0, dw0ss, pw0raw, part_pw0, 4818, 594);
    red_kernel<<<1, 128, 0, stream>>>(part_pw0, g_pw0, b_pw0, pw0ss, 64, 1.f / 4096.f);
    // ---- Level 1: C=98, 64x64, out 32 ----
    fused_dw_kernel<1, true><<<4 * 98 * 16, 256, 0, stream>>>(
        f0, pw0raw, pw0ss, w1, bigA, part_dw1);
    red_kernel<<<1, 128, 0, stream>>>(part_dw1, g_dw1, b_dw1, dw1ss, 98, 1.f / 16384.f);
    pw_small_kernel<98, 32, 64, 64, 4><<<256, 256, 0, stream>>>(
        bigA, w1, dw1ss, pw1raw, part_pw1, 4018, 882);
    red_kernel<<<1, 128, 0, stream>>>(part_pw1, g_pw1, b_pw1, pw1ss, 32, 1.f / 16384.f);
    // ---- Level 2: C=37, 256x256, out 21 ----
    dw2_col_kernel<<<4 * 37 * 32, 256, 0, stream>>>(
        x_img, pw1raw, pw1ss, w2, bigA, part_dw2);
    red_kernel<<<1, 128, 0, stream>>>(part_dw2, g_dw2, b_dw2, dw2ss, 37, 1.f / 262144.f);
    pw2_kernel<<<1024, 256, 0, stream>>>(bigA, w2, dw2ss, out, part_pw2);
    red_kernel<<<1, 128, 0, stream>>>(part_pw2, g_pw2, b_pw2, pw2ss, 21, 1.f / 262144.f);
    finalbn_kernel<<<5376, 256, 0, stream>>>(out, pw2ss);
}

// Round 12
// 143.983 us; speedup vs baseline: 9.2503x; 1.0113x over previous
//
#include <hip/hip_runtime.h>
#include <hip/hip_bf16.h>

#define EPS 1e-5f

__device__ __forceinline__ int reflect_idx(int i, int n) {
    if (i < 0) return -i;
    if (i >= n) return 2 * n - 2 - i;
    return i;
}

__device__ __forceinline__ float bilin(const float* __restrict__ pb, int Hp, float sy, float sx) {
    int y0 = (int)floorf(sy), x0 = (int)floorf(sx);
    float fy = sy - y0, fx = sx - x0;
    int y0c = min(max(y0, 0), Hp - 1), y1c = min(max(y0 + 1, 0), Hp - 1);
    int x0c = min(max(x0, 0), Hp - 1), x1c = min(max(x0 + 1, 0), Hp - 1);
    float v00 = pb[y0c * Hp + x0c], v01 = pb[y0c * Hp + x1c];
    float v10 = pb[y1c * Hp + x0c], v11 = pb[y1c * Hp + x1c];
    return v00 * (1 - fy) * (1 - fx) + v01 * (1 - fy) * fx
         + v10 * fy * (1 - fx) + v11 * fy * fx;
}

// ---------------- Fused build + depthwise 3x3 + striped stats (levels 0/1) ----------------
template <int LEVEL, bool WRITE>
__global__ __launch_bounds__(256)
void fused_dw_kernel(const float* __restrict__ feat, const float* __restrict__ prev,
                     const float* __restrict__ pss, const float* __restrict__ wsig,
                     float* __restrict__ out, float* __restrict__ part) {
    constexpr int C    = LEVEL == 0 ? 66 : 98;
    constexpr int H    = LEVEL == 0 ? 32 : 64;
    constexpr int TILE = 16;
    constexpr int NT   = H / TILE;
    constexpr int PXPT = (TILE * TILE) / 256;
    constexpr int WC   = LEVEL == 0 ? 4818 : 4018;
    constexpr int NF   = LEVEL == 0 ? 64 : 32;
    constexpr int Hp   = 32;
    constexpr int Cp   = 64;
    constexpr int P    = H / 8;
    constexpr float SC = 0.5f;
    constexpr int HS   = TILE + 2;

    __shared__ float sh[HS * HS];
    int tid = threadIdx.x, bid = blockIdx.x;
    int tile = bid % (NT * NT);
    int c = (bid / (NT * NT)) % C;
    int b = bid / (NT * NT * C);
    int ty0 = (tile / NT) * TILE, tx0 = (tile % NT) * TILE;

    for (int i = tid; i < HS * HS; i += 256) {
        int h = reflect_idx(ty0 - 1 + i / HS, H);
        int w = reflect_idx(tx0 - 1 + i % HS, H);
        float val;
        if (c == 0)      val = -1.f + 2.f * w / (H - 1);
        else if (c == 1) val = -1.f + 2.f * h / (H - 1);
        else if (c < 2 + NF) val = feat[((size_t)(b * NF + c - 2) * H + h) * H + w];
        else {
            int o = c - 2 - NF;
            const float* pb = prev + (size_t)(b * Cp + o) * Hp * Hp;
            float raw = bilin(pb, Hp, (h + 0.5f) * SC - 0.5f, (w + 0.5f) * SC - 0.5f);
            val = raw * pss[2 * o] + pss[2 * o + 1];
        }
        sh[i] = val;
    }
    __syncthreads();

    float s1 = 0.f, s2 = 0.f;
    float* ob = out + (((size_t)(b * C + c)) * H + ty0) * H + tx0;
    float wreg[9];
    if constexpr (TILE == P) {
        const float* wb = wsig + ((size_t)(b * WC + c * 9)) * 64 + (ty0 / P) * 8 + (tx0 / P);
#pragma unroll
        for (int t = 0; t < 9; ++t) wreg[t] = wb[(size_t)t * 64];
    }
#pragma unroll
    for (int k = 0; k < PXPT; ++k) {
        int px = tid + k * 256;
        int tyy = px / TILE, txx = px % TILE;
        if constexpr (TILE != P) {
            int u = (ty0 + tyy) / P, vv = (tx0 + txx) / P;
            const float* wb = wsig + ((size_t)(b * WC + c * 9)) * 64 + u * 8 + vv;
#pragma unroll
            for (int t = 0; t < 9; ++t) wreg[t] = wb[(size_t)t * 64];
        }
        float acc = 0.f;
#pragma unroll
        for (int t = 0; t < 9; ++t)
            acc += wreg[t] * sh[(tyy + t / 3) * HS + txx + t % 3];
        if constexpr (WRITE) ob[tyy * H + txx] = acc;
        s1 += acc; s2 += acc * acc;
    }
#pragma unroll
    for (int off = 32; off; off >>= 1) {
        s1 += __shfl_xor(s1, off);
        s2 += __shfl_xor(s2, off);
    }
    __shared__ float r1[4], r2[4];
    int wave = tid >> 6;
    if ((tid & 63) == 0) { r1[wave] = s1; r2[wave] = s2; }
    __syncthreads();
    if (tid == 0) {
        int slot = bid & 63;
        atomicAdd(&part[slot * 2 * C + 2 * c],     r1[0] + r1[1] + r1[2] + r1[3]);
        atomicAdd(&part[slot * 2 * C + 2 * c + 1], r2[0] + r2[1] + r2[2] + r2[3]);
    }
}

// ---------------- Reduce 64-slot partials -> per-channel (scale, shift) ----------------
__global__ void red_kernel(const float* __restrict__ part, const float* __restrict__ g,
                           const float* __restrict__ bb, float* __restrict__ ss,
                           int C, float invN) {
    int c = threadIdx.x;
    if (c >= C) return;
    float s1 = 0.f, s2 = 0.f;
#pragma unroll 8
    for (int s = 0; s < 64; ++s) {
        s1 += part[s * 2 * C + 2 * c];
        s2 += part[s * 2 * C + 2 * c + 1];
    }
    float m = s1 * invN;
    float var = s2 * invN - m * m;
    float sc = g[c] * rsqrtf(var + EPS);
    ss[2 * c] = sc;
    ss[2 * c + 1] = bb[c] - m * sc;
}

// ---------------- Level-2 dw: column-per-thread, compile-time row-lerp fast path, bf16 out ----
__global__ __launch_bounds__(256)
void dw2_col_kernel(const float* __restrict__ ximg, const float* __restrict__ prev,
                    const float* __restrict__ pw1ss, const float* __restrict__ wsig,
                    __hip_bfloat16* __restrict__ out, float* __restrict__ part) {
    const int C = 37, H = 256, W = 256, WC = 1110, Hp = 64, Cp = 32;
    const int S = 260;
    __shared__ float sh[10 * S];
    __shared__ float pssl[64];
    __shared__ float lwv[72];
    __shared__ float r1[4], r2[4];

    int tid = threadIdx.x, bid = blockIdx.x;
    int rb = bid & 31;
    int c  = (bid >> 5) % C;
    int b  = bid / (32 * C);
    int ty0 = rb * 8;
    int u = rb >> 2;

    if (tid < 64) pssl[tid] = pw1ss[tid];
    if (tid < 72) {
        int v = tid / 9, t = tid - v * 9;
        lwv[tid] = wsig[((size_t)(b * WC + c * 9 + t)) * 64 + u * 8 + v];
    }
    __syncthreads();

    const float* pb   = (c >= 5) ? prev + (size_t)(b * Cp + (c - 5)) * Hp * Hp : nullptr;
    const float* xrow = (c >= 2 && c < 5) ? ximg + (size_t)(b * 3 + c - 2) * H * W : nullptr;
    float cx = -1.f + tid * (2.f / 255.f);
    float sxm = (tid + 0.5f) * 0.25f - 0.5f;
    int x0m = (int)floorf(sxm);
    float fxm = sxm - x0m;
    int x0cm = min(max(x0m, 0), Hp - 1), x1cm = min(max(x0m + 1, 0), Hp - 1);
    float psc = (c >= 5) ? pssl[2 * (c - 5)] : 0.f;
    float psh = (c >= 5) ? pssl[2 * (c - 5) + 1] : 0.f;

    if (c >= 5 && rb >= 1 && rb <= 30) {
        // Fast path: halo rows ty0-1..ty0+8 lerp between 4 source rows 2rb-1..2rb+2
        // with compile-time weights: j0={0,0,0,1,1,1,1,2,2,2}, fy cycle {.375,.625,.875,.125}.
        int y0b = 2 * rb - 1;
        const float* q0 = pb + (size_t)y0b * Hp;
        const float* q1 = q0 + Hp;
        const float* q2 = q1 + Hp;
        const float* q3 = q2 + Hp;
        float a0 = q0[x0cm] + (q0[x1cm] - q0[x0cm]) * fxm;
        float a1 = q1[x0cm] + (q1[x1cm] - q1[x0cm]) * fxm;
        float a2 = q2[x0cm] + (q2[x1cm] - q2[x0cm]) * fxm;
        float a3 = q3[x0cm] + (q3[x1cm] - q3[x0cm]) * fxm;
        sh[0 * S + tid + 1] = (a0 + (a1 - a0) * 0.375f) * psc + psh;
        sh[1 * S + tid + 1] = (a0 + (a1 - a0) * 0.625f) * psc + psh;
        sh[2 * S + tid + 1] = (a0 + (a1 - a0) * 0.875f) * psc + psh;
        sh[3 * S + tid + 1] = (a1 + (a2 - a1) * 0.125f) * psc + psh;
        sh[4 * S + tid + 1] = (a1 + (a2 - a1) * 0.375f) * psc + psh;
        sh[5 * S + tid + 1] = (a1 + (a2 - a1) * 0.625f) * psc + psh;
        sh[6 * S + tid + 1] = (a1 + (a2 - a1) * 0.875f) * psc + psh;
        sh[7 * S + tid + 1] = (a2 + (a3 - a2) * 0.125f) * psc + psh;
        sh[8 * S + tid + 1] = (a2 + (a3 - a2) * 0.375f) * psc + psh;
        sh[9 * S + tid + 1] = (a2 + (a3 - a2) * 0.625f) * psc + psh;
    } else {
#pragma unroll
        for (int r = 0; r < 10; ++r) {
            int h = reflect_idx(ty0 - 1 + r, H);
            float val;
            if (c == 0)      val = cx;
            else if (c == 1) val = -1.f + h * (2.f / 255.f);
            else if (c < 5)  val = xrow[h * W + tid];
            else {
                float sy = (h + 0.5f) * 0.25f - 0.5f;
                int y0 = (int)floorf(sy);
                float fy = sy - y0;
                int y0c = min(max(y0, 0), Hp - 1), y1c = min(max(y0 + 1, 0), Hp - 1);
                const float* q0 = pb + y0c * Hp;
                const float* q1 = pb + y1c * Hp;
                float a0 = q0[x0cm] + (q0[x1cm] - q0[x0cm]) * fxm;
                float a1 = q1[x0cm] + (q1[x1cm] - q1[x0cm]) * fxm;
                val = (a0 + (a1 - a0) * fy) * psc + psh;
            }
            sh[r * S + tid + 1] = val;
        }
    }
    if (tid < 20) {
        int r = tid >> 1, side = tid & 1;
        int wimg = side ? 254 : 1;               // reflect(-1)=1, reflect(256)=254
        int h = reflect_idx(ty0 - 1 + r, H);
        float val;
        if (c == 0)      val = -1.f + wimg * (2.f / 255.f);
        else if (c == 1) val = -1.f + h * (2.f / 255.f);
        else if (c < 5)  val = xrow[h * W + wimg];
        else {
            float sx = (wimg + 0.5f) * 0.25f - 0.5f;
            int x0 = (int)floorf(sx); float fx = sx - x0;
            int x0c = min(max(x0, 0), Hp - 1), x1c = min(max(x0 + 1, 0), Hp - 1);
            float sy = (h + 0.5f) * 0.25f - 0.5f;
            int y0 = (int)floorf(sy); float fy = sy - y0;
            int y0c = min(max(y0, 0), Hp - 1), y1c = min(max(y0 + 1, 0), Hp - 1);
            const float* q0 = pb + y0c * Hp;
            const float* q1 = pb + y1c * Hp;
            float a0 = q0[x0c] + (q0[x1c] - q0[x0c]) * fx;
            float a1 = q1[x0c] + (q1[x1c] - q1[x0c]) * fx;
            val = (a0 + (a1 - a0) * fy) * psc + psh;
        }
        sh[r * S + (side ? 257 : 0)] = val;
    }
    __syncthreads();

    int t = tid;
    int v = t >> 5;
    float wr[9];
#pragma unroll
    for (int tap = 0; tap < 9; ++tap) wr[tap] = lwv[v * 9 + tap];

    float px[8];
#pragma unroll
    for (int k = 0; k < 8; ++k) px[k] = 0.f;

#pragma unroll
    for (int r = 0; r < 10; ++r) {
        float L = sh[r * S + t];
        float M = sh[r * S + t + 1];
        float R = sh[r * S + t + 2];
#pragma unroll
        for (int dr = 0; dr < 3; ++dr) {
            int k = r - dr;
            if (k >= 0 && k < 8)
                px[k] += wr[dr * 3] * L + wr[dr * 3 + 1] * M + wr[dr * 3 + 2] * R;
        }
    }

    __hip_bfloat16* ob = out + (((size_t)(b * C + c)) * H + ty0) * W + t;
    float s1 = 0.f, s2 = 0.f;
#pragma unroll
    for (int k = 0; k < 8; ++k) {
        ob[k * W] = __float2bfloat16(px[k]);
        s1 += px[k]; s2 += px[k] * px[k];
    }
#pragma unroll
    for (int off = 32; off; off >>= 1) {
        s1 += __shfl_xor(s1, off);
        s2 += __shfl_xor(s2, off);
    }
    int wave = tid >> 6;
    if ((tid & 63) == 0) { r1[wave] = s1; r2[wave] = s2; }
    __syncthreads();
    if (tid == 0) {
        int slot = bid & 63;
        atomicAdd(&part[slot * 2 * C + 2 * c],     r1[0] + r1[1] + r1[2] + r1[3]);
        atomicAdd(&part[slot * 2 * C + 2 * c + 1], r2[0] + r2[1] + r2[2] + r2[3]);
    }
}

// ---------------- Pointwise 1x1, small levels (direct folded ss) ----------------
template <int C, int ONC, int H, int PX_T, int OC_T>
__global__ __launch_bounds__(256)
void pw_small_kernel(const float* __restrict__ x, const float* __restrict__ wsig,
                     const float* __restrict__ ss, float* __restrict__ out,
                     float* __restrict__ part, int WC, int ndw) {
    constexpr int P = H / 8;
    constexpr int OC_I = ONC / OC_T;
    __shared__ float lw[ONC * C];
    __shared__ float lx[C * PX_T];
    int tid = threadIdx.x, bid = blockIdx.x;
    int uv = bid & 63, b = bid >> 6;
    int u = uv >> 3, v = uv & 7;

    const size_t wbase = ((size_t)b * WC + ndw) * 64 + uv;
    for (int i = tid; i < ONC * C; i += 256) lw[i] = wsig[wbase + (size_t)i * 64];
    for (int i = tid; i < C * PX_T; i += 256) {
        int c = i / PX_T, pxl = i % PX_T;
        int h = u * P + pxl / P, w = v * P + pxl % P;
        float xv = x[(((size_t)b * C + c) * H + h) * H + w];
        lx[i] = fminf(fmaxf(xv * ss[2 * c] + ss[2 * c + 1], 0.f), 6.f);
    }
    __syncthreads();

    int px_id = tid % PX_T, oc_id = tid / PX_T;
    int h = u * P + px_id / P, w = v * P + px_id % P;
    float acc[OC_I];
#pragma unroll
    for (int oi = 0; oi < OC_I; ++oi) acc[oi] = 0.f;
    for (int c = 0; c < C; ++c) {
        float xv = lx[c * PX_T + px_id];
#pragma unroll
        for (int oi = 0; oi < OC_I; ++oi)
            acc[oi] += lw[(oc_id * OC_I + oi) * C + c] * xv;
    }
    float* ob = out + (((size_t)b * ONC) * H + h) * H + w;
#pragma unroll
    for (int oi = 0; oi < OC_I; ++oi)
        ob[(size_t)(oc_id * OC_I + oi) * H * H] = acc[oi];

    constexpr int GROUP = (PX_T < 64) ? PX_T : 64;
    int lane = tid & 63;
    int slot = bid & 63;
#pragma unroll
    for (int oi = 0; oi < OC_I; ++oi) {
        float s1 = acc[oi], s2 = acc[oi] * acc[oi];
#pragma unroll
        for (int off = GROUP / 2; off; off >>= 1) {
            s1 += __shfl_xor(s1, off);
            s2 += __shfl_xor(s2, off);
        }
        if ((lane & (GROUP - 1)) == 0) {
            int o = oc_id * OC_I + oi;
            atomicAdd(&part[slot * 2 * ONC + 2 * o], s1);
            atomicAdd(&part[slot * 2 * ONC + 2 * o + 1], s2);
        }
    }
}

// ---------------- Pointwise 1x1 level 2: bf16 input, 1024 blocks, direct dw2ss ----------------
__global__ __launch_bounds__(256)
void pw2_kernel(const __hip_bfloat16* __restrict__ x, const float* __restrict__ wsig,
                const float* __restrict__ dss,
                float* __restrict__ out, float* __restrict__ part) {
    const int C = 37, ONC = 21, H = 256, WC = 1110, NDW = 333;
    __shared__ float lw[777];
    __shared__ float ssl[74];
    __shared__ float r1[4][ONC], r2[4][ONC];
    int tid = threadIdx.x, bid = blockIdx.x;
    int chunk = bid & 3;
    int uv = (bid >> 2) & 63;
    int b = bid >> 8;
    int y0 = (uv >> 3) * 32 + chunk * 8, x0 = (uv & 7) * 32;

    for (int i = tid; i < 777; i += 256) lw[i] = wsig[((size_t)(b * WC + NDW) + i) * 64 + uv];
    if (tid < 74) ssl[tid] = dss[tid];
    __syncthreads();

    int row = tid >> 5, col = tid & 31;
    const __hip_bfloat16* xb = x + (((size_t)(b * C)) * H + y0 + row) * H + x0 + col;
    float acc[ONC];
#pragma unroll
    for (int o = 0; o < ONC; ++o) acc[o] = 0.f;

    for (int c = 0; c < C; ++c) {
        float xv = __bfloat162float(xb[(size_t)c * H * H]);
        xv = fminf(fmaxf(xv * ssl[2 * c] + ssl[2 * c + 1], 0.f), 6.f);
#pragma unroll
        for (int o = 0; o < ONC; ++o)
            acc[o] += lw[o * C + c] * xv;
    }
    float* ob = out + (((size_t)(b * ONC)) * H + y0 + row) * H + x0 + col;
#pragma unroll
    for (int o = 0; o < ONC; ++o) ob[(size_t)o * H * H] = acc[o];

    int wave = tid >> 6, lane = tid & 63;
#pragma unroll
    for (int o = 0; o < ONC; ++o) {
        float s1 = acc[o], s2 = acc[o] * acc[o];
#pragma unroll
        for (int off = 32; off; off >>= 1) {
            s1 += __shfl_xor(s1, off);
            s2 += __shfl_xor(s2, off);
        }
        if (lane == 0) { r1[wave][o] = s1; r2[wave][o] = s2; }
    }
    __syncthreads();
    int slot = bid & 63;
    for (int o = tid; o < ONC; o += 256) {
        atomicAdd(&part[slot * 42 + 2 * o],     r1[0][o] + r1[1][o] + r1[2][o] + r1[3][o]);
        atomicAdd(&part[slot * 42 + 2 * o + 1], r2[0][o] + r2[1][o] + r2[2][o] + r2[3][o]);
    }
}

// ---------------- Final in-place BN (float4, direct pw2ss) ----------------
__global__ void finalbn_kernel(float* __restrict__ out, const float* __restrict__ ss) {
    int idx = blockIdx.x * 256 + threadIdx.x;
    const int total4 = 4 * 21 * 256 * 256 / 4;
    if (idx >= total4) return;
    int c = (idx / (256 * 256 / 4)) % 21;
    float4 v = ((float4*)out)[idx];
    float sc = ss[2 * c], sb = ss[2 * c + 1];
    v.x = v.x * sc + sb; v.y = v.y * sc + sb; v.z = v.z * sc + sb; v.w = v.w * sc + sb;
    ((float4*)out)[idx] = v;
}

extern "C" void kernel_launch(void* const* d_in, const int* in_sizes, int n_in,
                              void* d_out, int out_size, void* d_ws, size_t ws_size,
                              hipStream_t stream) {
    const float* x_img = (const float*)d_in[0];
    const float* f0    = (const float*)d_in[1];
    const float* f1    = (const float*)d_in[2];
    const float* w0    = (const float*)d_in[3];
    const float* w1    = (const float*)d_in[4];
    const float* w2    = (const float*)d_in[5];
    const float* g_dw0 = (const float*)d_in[6],  *b_dw0 = (const float*)d_in[7];
    const float* g_pw0 = (const float*)d_in[8],  *b_pw0 = (const float*)d_in[9];
    const float* g_dw1 = (const float*)d_in[10], *b_dw1 = (const float*)d_in[11];
    const float* g_pw1 = (const float*)d_in[12], *b_pw1 = (const float*)d_in[13];
    const float* g_dw2 = (const float*)d_in[14], *b_dw2 = (const float*)d_in[15];
    const float* g_pw2 = (const float*)d_in[16], *b_pw2 = (const float*)d_in[17];
    float* out = (float*)d_out;
    float* ws = (float*)d_ws;

    // workspace layout (floats)
    float* part_dw0 = ws;              // 64*132 = 8448
    float* part_pw0 = ws + 8448;       // 64*128 = 8192
    float* part_dw1 = ws + 16640;      // 64*196 = 12544
    float* part_pw1 = ws + 29184;      // 64*64  = 4096
    float* part_dw2 = ws + 33280;      // 64*74  = 4736
    float* part_pw2 = ws + 38016;      // 64*42  = 2688  -> parts end 40704
    float* dw0ss = ws + 40704;         // 132
    float* pw0ss = ws + 40836;         // 128
    float* dw1ss = ws + 40964;         // 196
    float* pw1ss = ws + 41160;         // 64
    float* dw2ss = ws + 41224;         // 74
    float* pw2ss = ws + 41298;         // 42 -> 41340
    float* pw0raw = ws + 41344;        // 4*64*32*32 = 262144
    float* pw1raw = pw0raw + 262144;   // 4*32*64*64 = 524288
    float* bigA   = pw1raw + 524288;   // levels 0/1 dw raw (fp32)
    __hip_bfloat16* bigAb = (__hip_bfloat16*)bigA;  // level 2 dw raw (bf16)

    hipMemsetAsync(ws, 0, 40704 * sizeof(float), stream);

    // ---- Level 0: C=66, 32x32, out 64 ----
    fused_dw_kernel<0, true><<<4 * 66 * 4, 256, 0, stream>>>(
        f1, nullptr, nullptr, w0, bigA, part_dw0);
    red_kernel<<<1, 128, 0, stream>>>(part_dw0, g_dw0, b_dw0, dw0ss, 66, 1.f / 4096.f);
    pw_small_kernel<66, 64, 32, 16, 16><<<256, 256, 0, stream>>>(
        bigA, w0, dw0ss, pw0raw, part_pw0, 4818, 594);
    red_kernel<<<1, 128, 0, stream>>>(part_pw0, g_pw0, b_pw0, pw0ss, 64, 1.f / 4096.f);
    // ---- Level 1: C=98, 64x64, out 32 ----
    fused_dw_kernel<1, true><<<4 * 98 * 16, 256, 0, stream>>>(
        f0, pw0raw, pw0ss, w1, bigA, part_dw1);
    red_kernel<<<1, 128, 0, stream>>>(part_dw1, g_dw1, b_dw1, dw1ss, 98, 1.f / 16384.f);
    pw_small_kernel<98, 32, 64, 64, 4><<<256, 256, 0, stream>>>(
        bigA, w1, dw1ss, pw1raw, part_pw1, 4018, 882);
    red_kernel<<<1, 128, 0, stream>>>(part_pw1, g_pw1, b_pw1, pw1ss, 32, 1.f / 16384.f);
    // ---- Level 2: C=37, 256x256, out 21 ----
    dw2_col_kernel<<<4 * 37 * 32, 256, 0, stream>>>(
        x_img, pw1raw, pw1ss, w2, bigAb, part_dw2);
    red_kernel<<<1, 128, 0, stream>>>(part_dw2, g_dw2, b_dw2, dw2ss, 37, 1.f / 262144.f);
    pw2_kernel<<<1024, 256, 0, stream>>>(bigAb, w2, dw2ss, out, part_pw2);
    red_kernel<<<1, 128, 0, stream>>>(part_pw2, g_pw2, b_pw2, pw2ss, 21, 1.f / 262144.f);
    finalbn_kernel<<<5376, 256, 0, stream>>>(out, pw2ss);
}